// Round 11
// baseline (1048.472 us; speedup 1.0000x reference)
//
#include <hip/hip_runtime.h>
#include <math.h>

#define NN 20000
#define EE 640000
#define DD 64

#define CNT_BLK 2500   // EE / 256 exactly
#define K1_HBLK 2250   // nodes 0..8999      (4 nodes / 256-thr block)
#define K2_NODE0 9000
#define K2_HBLK 500    // nodes 9000..16999  (16 nodes / 1024-thr block)
#define K3_NODE0 17000
#define K3_HBLK 750    // nodes 17000..19999 (4 nodes / 256-thr block)

typedef float f4v __attribute__((ext_vector_type(4)));
__device__ __forceinline__ float4 nt_load4(const float* p) {
  f4v v = __builtin_nontemporal_load((const f4v*)p);
  return make_float4(v.x, v.y, v.z, v.w);
}

// ---------------- gat_h body: h[n] = x[n] @ w[n], s_self[n] = h[n]·a[n,0:64] ----------------

__device__ __forceinline__ void gat_h_node(int n, int lane,
                                           const float* __restrict__ xin,
                                           const float* __restrict__ w,
                                           const float* __restrict__ a,
                                           float* __restrict__ h,
                                           float* __restrict__ s_self,
                                           int relu_in) {
  float xv = xin[(size_t)n * DD + lane];
  if (relu_in) xv = fmaxf(xv, 0.f);

  const float* wbase = w + (size_t)n * DD * DD;
  int oq = lane & 15;
  int isub = lane >> 4;
  float4 acc = make_float4(0.f, 0.f, 0.f, 0.f);
#pragma unroll
  for (int ib = 0; ib < 16; ++ib) {
    float4 wv = nt_load4(wbase + (size_t)(ib * 64 + lane) * 4);
    float xi = __shfl(xv, ib * 4 + isub);
    acc.x += xi * wv.x;
    acc.y += xi * wv.y;
    acc.z += xi * wv.z;
    acc.w += xi * wv.w;
  }
#pragma unroll
  for (int m = 16; m <= 32; m <<= 1) {
    acc.x += __shfl_xor(acc.x, m);
    acc.y += __shfl_xor(acc.y, m);
    acc.z += __shfl_xor(acc.z, m);
    acc.w += __shfl_xor(acc.w, m);
  }
  if (lane < 16) {
    *(float4*)(h + (size_t)n * DD + oq * 4) = acc;
  }
  const float4* a4 = (const float4*)(a + (size_t)n * 2 * DD);
  float4 av = a4[oq];
  float p = acc.x * av.x + acc.y * av.y + acc.z * av.z + acc.w * av.w;
  if (lane >= 16) p = 0.f;
#pragma unroll
  for (int m = 1; m < 64; m <<= 1) p += __shfl_xor(p, m);
  if (lane == 0) s_self[n] = p;
}

// ---------------- K1: edge-count atomics ∥ gat_h L1 nodes [0, 9000) ----------------

__global__ __launch_bounds__(256) void k1_count_h(const int* __restrict__ col,
                                                  int* __restrict__ deg,
                                                  const float* __restrict__ x,
                                                  const float* __restrict__ w0,
                                                  const float* __restrict__ a0,
                                                  float* __restrict__ h,
                                                  float* __restrict__ s_self) {
  if (blockIdx.x < CNT_BLK) {
    int e = blockIdx.x * 256 + threadIdx.x;
    atomicAdd(&deg[col[e]], 1);
  } else {
    int n = ((int)blockIdx.x - CNT_BLK) * 4 + (threadIdx.x >> 6);
    gat_h_node(n, threadIdx.x & 63, x, w0, a0, h, s_self, 0);
  }
}

// ---------------- K2: single-block scan ∥ gat_h L1 nodes [9000, 17000) ----------------

__global__ __launch_bounds__(1024) void k2_scan_h(const int* __restrict__ deg,
                                                  int* __restrict__ offs,
                                                  int* __restrict__ cursor,
                                                  const float* __restrict__ x,
                                                  const float* __restrict__ w0,
                                                  const float* __restrict__ a0,
                                                  float* __restrict__ h,
                                                  float* __restrict__ s_self) {
  if (blockIdx.x == 0) {
    __shared__ int part[1024];
    int t = threadIdx.x;
    const int CH = (NN + 1023) / 1024;  // 20
    int base = t * CH;
    int sum = 0;
    for (int i = 0; i < CH; ++i) {
      int idx = base + i;
      if (idx < NN) sum += deg[idx];
    }
    part[t] = sum;
    __syncthreads();
    for (int off = 1; off < 1024; off <<= 1) {
      int v = (t >= off) ? part[t - off] : 0;
      __syncthreads();
      part[t] += v;
      __syncthreads();
    }
    int run = (t == 0) ? 0 : part[t - 1];
    for (int i = 0; i < CH; ++i) {
      int idx = base + i;
      if (idx < NN) {
        offs[idx] = run;
        cursor[idx] = run;
        run += deg[idx];
      }
    }
    if (t == 1023) offs[NN] = part[1023];
  } else {
    int n = K2_NODE0 + ((int)blockIdx.x - 1) * 16 + ((int)threadIdx.x >> 6);
    gat_h_node(n, threadIdx.x & 63, x, w0, a0, h, s_self, 0);
  }
}

// ---------------- K3: CSR scatter ∥ gat_h L1 nodes [17000, 20000) ----------------

__global__ __launch_bounds__(256) void k3_scatter_h(const int* __restrict__ row,
                                                    const int* __restrict__ col,
                                                    int* __restrict__ cursor,
                                                    int* __restrict__ src,
                                                    const float* __restrict__ x,
                                                    const float* __restrict__ w0,
                                                    const float* __restrict__ a0,
                                                    float* __restrict__ h,
                                                    float* __restrict__ s_self) {
  if (blockIdx.x < CNT_BLK) {
    int e = blockIdx.x * 256 + threadIdx.x;
    int pos = atomicAdd(&cursor[col[e]], 1);
    src[pos] = row[e];
  } else {
    int n = K3_NODE0 + ((int)blockIdx.x - CNT_BLK) * 4 + (threadIdx.x >> 6);
    gat_h_node(n, threadIdx.x & 63, x, w0, a0, h, s_self, 0);
  }
}

// ---------------- agg edge loop: 16 edges / macro-iter (4 per 16-lane group) ----------------

__device__ __forceinline__ void agg_edges(const float* __restrict__ h,
                                          const float* __restrict__ s_self,
                                          const float* __restrict__ a,
                                          const int* __restrict__ src,
                                          int s0, int s1, int g, int q, float4 hn,
                                          float4& acc, float& ssum) {
  int r[4];
#pragma unroll
  for (int k = 0; k < 4; ++k) {
    int e = s0 + 4 * k + g;
    r[k] = (e < s1) ? src[e] : -1;
  }
  for (int base = s0; base < s1; base += 16) {
    int rc0 = r[0], rc1 = r[1], rc2 = r[2], rc3 = r[3];
    int i0 = rc0 < 0 ? 0 : rc0;
    int i1 = rc1 < 0 ? 0 : rc1;
    int i2 = rc2 < 0 ? 0 : rc2;
    int i3 = rc3 < 0 ? 0 : rc3;
    float4 av0 = *(const float4*)(a + (size_t)i0 * 2 * DD + DD + q * 4);
    float4 av1 = *(const float4*)(a + (size_t)i1 * 2 * DD + DD + q * 4);
    float4 av2 = *(const float4*)(a + (size_t)i2 * 2 * DD + DD + q * 4);
    float4 av3 = *(const float4*)(a + (size_t)i3 * 2 * DD + DD + q * 4);
    float4 hr0 = *(const float4*)(h + (size_t)i0 * DD + q * 4);
    float4 hr1 = *(const float4*)(h + (size_t)i1 * DD + q * 4);
    float4 hr2 = *(const float4*)(h + (size_t)i2 * DD + q * 4);
    float4 hr3 = *(const float4*)(h + (size_t)i3 * DD + q * 4);
    float ss0 = s_self[i0];
    float ss1 = s_self[i1];
    float ss2 = s_self[i2];
    float ss3 = s_self[i3];
#pragma unroll
    for (int k = 0; k < 4; ++k) {
      int e = base + 16 + 4 * k + g;
      r[k] = (e < s1) ? src[e] : -1;
    }
#pragma unroll
    for (int k = 0; k < 4; ++k) {
      float4 av = (k == 0) ? av0 : (k == 1) ? av1 : (k == 2) ? av2 : av3;
      float4 hr = (k == 0) ? hr0 : (k == 1) ? hr1 : (k == 2) ? hr2 : hr3;
      float ss = (k == 0) ? ss0 : (k == 1) ? ss1 : (k == 2) ? ss2 : ss3;
      int rc = (k == 0) ? rc0 : (k == 1) ? rc1 : (k == 2) ? rc2 : rc3;
      float p = av.x * hn.x + av.y * hn.y + av.z * hn.z + av.w * hn.w;
      p += __shfl_xor(p, 1);
      p += __shfl_xor(p, 2);
      p += __shfl_xor(p, 4);
      p += __shfl_xor(p, 8);
      float sc = ss + p;
      sc = sc > 0.f ? sc : 0.2f * sc;  // leaky_relu 0.2
      float ex = (rc >= 0) ? __expf(sc) : 0.f;
      acc.x += ex * hr.x;
      acc.y += ex * hr.y;
      acc.z += ex * hr.z;
      acc.w += ex * hr.w;
      ssum += ex;
    }
  }
}

// ---------------- fused: agg(L1) + relu + matvec(w1) + s_self2 ----------------

__global__ __launch_bounds__(256) void fused_agg_h(const float* __restrict__ h1,
                                                   const float* __restrict__ s_self1,
                                                   const float* __restrict__ a0,
                                                   const int* __restrict__ offs,
                                                   const int* __restrict__ src,
                                                   const float* __restrict__ b0,
                                                   const float* __restrict__ w1,
                                                   const float* __restrict__ a1,
                                                   float* __restrict__ h2,
                                                   float* __restrict__ s_self2) {
  int widx = threadIdx.x >> 6;
  int lane = threadIdx.x & 63;
  int n = blockIdx.x * 4 + widx;  // NN % 4 == 0
  int g = lane >> 4;
  int q = lane & 15;

  float4 hn = *(const float4*)(h1 + (size_t)n * DD + q * 4);

  int s0 = offs[n], s1 = offs[n + 1];
  float4 acc = make_float4(0.f, 0.f, 0.f, 0.f);
  float ssum = 0.f;
  agg_edges(h1, s_self1, a0, src, s0, s1, g, q, hn, acc, ssum);
#pragma unroll
  for (int m = 16; m <= 32; m <<= 1) {
    acc.x += __shfl_xor(acc.x, m);
    acc.y += __shfl_xor(acc.y, m);
    acc.z += __shfl_xor(acc.z, m);
    acc.w += __shfl_xor(acc.w, m);
    ssum += __shfl_xor(ssum, m);
  }
  float4 b4 = *(const float4*)(b0 + (size_t)n * DD + q * 4);
  float inv = (s1 > s0) ? 1.f / ssum : 0.f;
  float4 o;
  o.x = b4.x + acc.x * inv;
  o.y = b4.y + acc.y * inv;
  o.z = b4.z + acc.z * inv;
  o.w = b4.w + acc.w * inv;

  int sl = lane >> 2, c = lane & 3;
  float ox = __shfl(o.x, sl);
  float oy = __shfl(o.y, sl);
  float oz = __shfl(o.z, sl);
  float ow = __shfl(o.w, sl);
  float xv = (c == 0) ? ox : (c == 1) ? oy : (c == 2) ? oz : ow;
  xv = fmaxf(xv, 0.f);  // relu between layers

  const float* wbase = w1 + (size_t)n * DD * DD;
  float4 macc = make_float4(0.f, 0.f, 0.f, 0.f);
#pragma unroll
  for (int ib = 0; ib < 16; ++ib) {
    float4 wv = nt_load4(wbase + (size_t)(ib * 64 + lane) * 4);
    float xi = __shfl(xv, ib * 4 + g);
    macc.x += xi * wv.x;
    macc.y += xi * wv.y;
    macc.z += xi * wv.z;
    macc.w += xi * wv.w;
  }
#pragma unroll
  for (int m = 16; m <= 32; m <<= 1) {
    macc.x += __shfl_xor(macc.x, m);
    macc.y += __shfl_xor(macc.y, m);
    macc.z += __shfl_xor(macc.z, m);
    macc.w += __shfl_xor(macc.w, m);
  }
  if (lane < 16) {
    *(float4*)(h2 + (size_t)n * DD + q * 4) = macc;
  }
  const float4* a4 = (const float4*)(a1 + (size_t)n * 2 * DD);
  float4 av1 = a4[q];
  float p2 = macc.x * av1.x + macc.y * av1.y + macc.z * av1.z + macc.w * av1.w;
  if (lane >= 16) p2 = 0.f;
#pragma unroll
  for (int m = 1; m < 64; m <<= 1) p2 += __shfl_xor(p2, m);
  if (lane == 0) s_self2[n] = p2;
}

// ---------------- layer-2 aggregate -> d_out ----------------

__global__ __launch_bounds__(256) void gat_agg(const float* __restrict__ h,
                                               const float* __restrict__ s_self,
                                               const float* __restrict__ a,
                                               const int* __restrict__ offs,
                                               const int* __restrict__ src,
                                               const float* __restrict__ bias,
                                               float* __restrict__ out) {
  int widx = threadIdx.x >> 6;
  int lane = threadIdx.x & 63;
  int n = blockIdx.x * 4 + widx;
  int g = lane >> 4;
  int q = lane & 15;

  float4 hn = *(const float4*)(h + (size_t)n * DD + q * 4);

  int s0 = offs[n], s1 = offs[n + 1];
  float4 acc = make_float4(0.f, 0.f, 0.f, 0.f);
  float ssum = 0.f;
  agg_edges(h, s_self, a, src, s0, s1, g, q, hn, acc, ssum);
#pragma unroll
  for (int m = 16; m <= 32; m <<= 1) {
    acc.x += __shfl_xor(acc.x, m);
    acc.y += __shfl_xor(acc.y, m);
    acc.z += __shfl_xor(acc.z, m);
    acc.w += __shfl_xor(acc.w, m);
    ssum += __shfl_xor(ssum, m);
  }
  if (lane < 16) {
    float4 b4 = *(const float4*)(bias + (size_t)n * DD + q * 4);
    float inv = (s1 > s0) ? 1.f / ssum : 0.f;
    float4 o;
    o.x = b4.x + acc.x * inv;
    o.y = b4.y + acc.y * inv;
    o.z = b4.z + acc.z * inv;
    o.w = b4.w + acc.w * inv;
    *(float4*)(out + (size_t)n * DD + q * 4) = o;
  }
}

// ---------------- launch: ATTRIBUTION PROBE — full pipeline run TWICE ----------------
// 2nd pass recomputes identical outputs (idempotent). kernels_total = dur(2x) - dur(1x);
// harness overhead = 2*dur(1x) - dur(2x). Decides H1 (harness floor) vs H2 (kernels).

extern "C" void kernel_launch(void* const* d_in, const int* in_sizes, int n_in,
                              void* d_out, int out_size, void* d_ws, size_t ws_size,
                              hipStream_t stream) {
  const float* x = (const float*)d_in[0];
  const int* edge = (const int*)d_in[1];
  const float* w0 = (const float*)d_in[2];
  const float* a0 = (const float*)d_in[3];
  const float* b0 = (const float*)d_in[4];
  const float* w1 = (const float*)d_in[5];
  const float* a1 = (const float*)d_in[6];
  const float* b1 = (const float*)d_in[7];
  float* out = (float*)d_out;

  const int* row = edge;       // edge_index[0]
  const int* col = edge + EE;  // edge_index[1]

  char* p = (char*)d_ws;
  float* h1 = (float*)p;      p += (size_t)NN * DD * 4;
  float* h2 = (float*)p;      p += (size_t)NN * DD * 4;
  float* s_self1 = (float*)p; p += (size_t)NN * 4;
  float* s_self2 = (float*)p; p += (size_t)NN * 4;
  int* deg = (int*)p;         p += (size_t)NN * 4;
  int* offs = (int*)p;        p += (size_t)(NN + 1) * 4;
  int* cursor = (int*)p;      p += (size_t)NN * 4;
  int* src = (int*)p;         p += (size_t)EE * 4;

  for (int rep = 0; rep < 2; ++rep) {
    hipMemsetAsync(deg, 0, (size_t)NN * 4, stream);
    k1_count_h<<<CNT_BLK + K1_HBLK, 256, 0, stream>>>(col, deg, x, w0, a0, h1, s_self1);
    k2_scan_h<<<1 + K2_HBLK, 1024, 0, stream>>>(deg, offs, cursor, x, w0, a0, h1, s_self1);
    k3_scatter_h<<<CNT_BLK + K3_HBLK, 256, 0, stream>>>(row, col, cursor, src, x, w0, a0, h1, s_self1);
    fused_agg_h<<<NN / 4, 256, 0, stream>>>(h1, s_self1, a0, offs, src, b0, w1, a1, h2, s_self2);
    gat_agg<<<NN / 4, 256, 0, stream>>>(h2, s_self2, a1, offs, src, b1, out);
  }
}

// Round 12
// 745.348 us; speedup vs baseline: 1.4067x; 1.4067x over previous
//
#include <hip/hip_runtime.h>
#include <math.h>

#define NN 20000
#define EE 640000
#define DD 64

#define CNT_BLK 2500   // EE / 256 exactly
#define K1_HBLK 2250   // nodes 0..8999      (4 nodes / 256-thr block)
#define CVT_BLK 5000   // NN*DD/256 fp16 convert blocks (a0h, a1h)
#define K2_NODE0 9000
#define K2_HBLK 500    // nodes 9000..16999  (16 nodes / 1024-thr block)
#define K3_NODE0 17000
#define K3_HBLK 750    // nodes 17000..19999 (4 nodes / 256-thr block)

typedef float f4v __attribute__((ext_vector_type(4)));
typedef _Float16 h4v __attribute__((ext_vector_type(4)));

__device__ __forceinline__ float4 nt_load4(const float* p) {
  f4v v = __builtin_nontemporal_load((const f4v*)p);
  return make_float4(v.x, v.y, v.z, v.w);
}

// ---------------- gat_h body: h[n] = x[n] @ w[n] (fp32 + fp16 shadow), s_self ----------------

__device__ __forceinline__ void gat_h_node(int n, int lane,
                                           const float* __restrict__ xin,
                                           const float* __restrict__ w,
                                           const float* __restrict__ a,
                                           float* __restrict__ h,
                                           _Float16* __restrict__ hh,
                                           float* __restrict__ s_self,
                                           int relu_in) {
  float xv = xin[(size_t)n * DD + lane];
  if (relu_in) xv = fmaxf(xv, 0.f);

  const float* wbase = w + (size_t)n * DD * DD;
  int oq = lane & 15;
  int isub = lane >> 4;
  float4 acc = make_float4(0.f, 0.f, 0.f, 0.f);
#pragma unroll
  for (int ib = 0; ib < 16; ++ib) {
    float4 wv = nt_load4(wbase + (size_t)(ib * 64 + lane) * 4);
    float xi = __shfl(xv, ib * 4 + isub);
    acc.x += xi * wv.x;
    acc.y += xi * wv.y;
    acc.z += xi * wv.z;
    acc.w += xi * wv.w;
  }
#pragma unroll
  for (int m = 16; m <= 32; m <<= 1) {
    acc.x += __shfl_xor(acc.x, m);
    acc.y += __shfl_xor(acc.y, m);
    acc.z += __shfl_xor(acc.z, m);
    acc.w += __shfl_xor(acc.w, m);
  }
  if (lane < 16) {
    *(float4*)(h + (size_t)n * DD + oq * 4) = acc;
    h4v hv = {(_Float16)acc.x, (_Float16)acc.y, (_Float16)acc.z, (_Float16)acc.w};
    *(h4v*)(hh + (size_t)n * DD + oq * 4) = hv;
  }
  const float4* a4 = (const float4*)(a + (size_t)n * 2 * DD);
  float4 av = a4[oq];
  float p = acc.x * av.x + acc.y * av.y + acc.z * av.z + acc.w * av.w;
  if (lane >= 16) p = 0.f;
#pragma unroll
  for (int m = 1; m < 64; m <<= 1) p += __shfl_xor(p, m);
  if (lane == 0) s_self[n] = p;
}

// ---------------- K1: count ∥ matvec [0,9000) ∥ fp16 convert of a0/a1 2nd half ----------------

__global__ __launch_bounds__(256) void k1_count_h(const int* __restrict__ col,
                                                  int* __restrict__ deg,
                                                  const float* __restrict__ x,
                                                  const float* __restrict__ w0,
                                                  const float* __restrict__ a0,
                                                  const float* __restrict__ a1,
                                                  float* __restrict__ h,
                                                  _Float16* __restrict__ hh,
                                                  float* __restrict__ s_self,
                                                  _Float16* __restrict__ a0h,
                                                  _Float16* __restrict__ a1h) {
  if (blockIdx.x < CNT_BLK) {
    int e = blockIdx.x * 256 + threadIdx.x;
    atomicAdd(&deg[col[e]], 1);
  } else if (blockIdx.x < CNT_BLK + K1_HBLK) {
    int n = ((int)blockIdx.x - CNT_BLK) * 4 + (threadIdx.x >> 6);
    gat_h_node(n, threadIdx.x & 63, x, w0, a0, h, hh, s_self, 0);
  } else {
    int i = ((int)blockIdx.x - CNT_BLK - K1_HBLK) * 256 + (int)threadIdx.x;
    int nrow = i >> 6, j = i & 63;
    size_t srcix = (size_t)nrow * 2 * DD + DD + j;
    a0h[i] = (_Float16)a0[srcix];
    a1h[i] = (_Float16)a1[srcix];
  }
}

// ---------------- K2: single-block scan ∥ matvec [9000, 17000) ----------------

__global__ __launch_bounds__(1024) void k2_scan_h(const int* __restrict__ deg,
                                                  int* __restrict__ offs,
                                                  int* __restrict__ cursor,
                                                  const float* __restrict__ x,
                                                  const float* __restrict__ w0,
                                                  const float* __restrict__ a0,
                                                  float* __restrict__ h,
                                                  _Float16* __restrict__ hh,
                                                  float* __restrict__ s_self) {
  if (blockIdx.x == 0) {
    __shared__ int part[1024];
    int t = threadIdx.x;
    const int CH = (NN + 1023) / 1024;  // 20
    int base = t * CH;
    int sum = 0;
    for (int i = 0; i < CH; ++i) {
      int idx = base + i;
      if (idx < NN) sum += deg[idx];
    }
    part[t] = sum;
    __syncthreads();
    for (int off = 1; off < 1024; off <<= 1) {
      int v = (t >= off) ? part[t - off] : 0;
      __syncthreads();
      part[t] += v;
      __syncthreads();
    }
    int run = (t == 0) ? 0 : part[t - 1];
    for (int i = 0; i < CH; ++i) {
      int idx = base + i;
      if (idx < NN) {
        offs[idx] = run;
        cursor[idx] = run;
        run += deg[idx];
      }
    }
    if (t == 1023) offs[NN] = part[1023];
  } else {
    int n = K2_NODE0 + ((int)blockIdx.x - 1) * 16 + ((int)threadIdx.x >> 6);
    gat_h_node(n, threadIdx.x & 63, x, w0, a0, h, hh, s_self, 0);
  }
}

// ---------------- K3: CSR scatter ∥ matvec [17000, 20000) ----------------

__global__ __launch_bounds__(256) void k3_scatter_h(const int* __restrict__ row,
                                                    const int* __restrict__ col,
                                                    int* __restrict__ cursor,
                                                    int* __restrict__ src,
                                                    const float* __restrict__ x,
                                                    const float* __restrict__ w0,
                                                    const float* __restrict__ a0,
                                                    float* __restrict__ h,
                                                    _Float16* __restrict__ hh,
                                                    float* __restrict__ s_self) {
  if (blockIdx.x < CNT_BLK) {
    int e = blockIdx.x * 256 + threadIdx.x;
    int pos = atomicAdd(&cursor[col[e]], 1);
    src[pos] = row[e];
  } else {
    int n = K3_NODE0 + ((int)blockIdx.x - CNT_BLK) * 4 + (threadIdx.x >> 6);
    gat_h_node(n, threadIdx.x & 63, x, w0, a0, h, hh, s_self, 0);
  }
}

// ---------------- agg edge loop: fp16 gathers (8B/lane), 16 edges / macro-iter ----------------

__device__ __forceinline__ void agg_edges(const _Float16* __restrict__ hh,
                                          const float* __restrict__ s_self,
                                          const _Float16* __restrict__ ah,
                                          const int* __restrict__ src,
                                          int s0, int s1, int g, int q, float4 hn,
                                          float4& acc, float& ssum) {
  int r[4];
#pragma unroll
  for (int k = 0; k < 4; ++k) {
    int e = s0 + 4 * k + g;
    r[k] = (e < s1) ? src[e] : -1;
  }
  for (int base = s0; base < s1; base += 16) {
    int rc0 = r[0], rc1 = r[1], rc2 = r[2], rc3 = r[3];
    int i0 = rc0 < 0 ? 0 : rc0;
    int i1 = rc1 < 0 ? 0 : rc1;
    int i2 = rc2 < 0 ? 0 : rc2;
    int i3 = rc3 < 0 ? 0 : rc3;
    h4v av0 = *(const h4v*)(ah + (size_t)i0 * DD + q * 4);
    h4v av1 = *(const h4v*)(ah + (size_t)i1 * DD + q * 4);
    h4v av2 = *(const h4v*)(ah + (size_t)i2 * DD + q * 4);
    h4v av3 = *(const h4v*)(ah + (size_t)i3 * DD + q * 4);
    h4v hr0 = *(const h4v*)(hh + (size_t)i0 * DD + q * 4);
    h4v hr1 = *(const h4v*)(hh + (size_t)i1 * DD + q * 4);
    h4v hr2 = *(const h4v*)(hh + (size_t)i2 * DD + q * 4);
    h4v hr3 = *(const h4v*)(hh + (size_t)i3 * DD + q * 4);
    float ss0 = s_self[i0];
    float ss1 = s_self[i1];
    float ss2 = s_self[i2];
    float ss3 = s_self[i3];
#pragma unroll
    for (int k = 0; k < 4; ++k) {
      int e = base + 16 + 4 * k + g;
      r[k] = (e < s1) ? src[e] : -1;
    }
#pragma unroll
    for (int k = 0; k < 4; ++k) {
      h4v av = (k == 0) ? av0 : (k == 1) ? av1 : (k == 2) ? av2 : av3;
      h4v hr = (k == 0) ? hr0 : (k == 1) ? hr1 : (k == 2) ? hr2 : hr3;
      float ss = (k == 0) ? ss0 : (k == 1) ? ss1 : (k == 2) ? ss2 : ss3;
      int rc = (k == 0) ? rc0 : (k == 1) ? rc1 : (k == 2) ? rc2 : rc3;
      float p = (float)av.x * hn.x + (float)av.y * hn.y + (float)av.z * hn.z + (float)av.w * hn.w;
      p += __shfl_xor(p, 1);
      p += __shfl_xor(p, 2);
      p += __shfl_xor(p, 4);
      p += __shfl_xor(p, 8);
      float sc = ss + p;
      sc = sc > 0.f ? sc : 0.2f * sc;  // leaky_relu 0.2
      float ex = (rc >= 0) ? __expf(sc) : 0.f;
      acc.x += ex * (float)hr.x;
      acc.y += ex * (float)hr.y;
      acc.z += ex * (float)hr.z;
      acc.w += ex * (float)hr.w;
      ssum += ex;
    }
  }
}

// ---------------- fused: agg(L1) + relu + matvec(w1) + s_self2 ----------------

__global__ __launch_bounds__(256) void fused_agg_h(const float* __restrict__ h1,
                                                   const _Float16* __restrict__ h1h,
                                                   const float* __restrict__ s_self1,
                                                   const _Float16* __restrict__ a0h,
                                                   const int* __restrict__ offs,
                                                   const int* __restrict__ src,
                                                   const float* __restrict__ b0,
                                                   const float* __restrict__ w1,
                                                   const float* __restrict__ a1,
                                                   float* __restrict__ h2,
                                                   _Float16* __restrict__ h2h,
                                                   float* __restrict__ s_self2) {
  int widx = threadIdx.x >> 6;
  int lane = threadIdx.x & 63;
  int n = blockIdx.x * 4 + widx;  // NN % 4 == 0
  int g = lane >> 4;
  int q = lane & 15;

  float4 hn = *(const float4*)(h1 + (size_t)n * DD + q * 4);

  int s0 = offs[n], s1 = offs[n + 1];
  float4 acc = make_float4(0.f, 0.f, 0.f, 0.f);
  float ssum = 0.f;
  agg_edges(h1h, s_self1, a0h, src, s0, s1, g, q, hn, acc, ssum);
#pragma unroll
  for (int m = 16; m <= 32; m <<= 1) {
    acc.x += __shfl_xor(acc.x, m);
    acc.y += __shfl_xor(acc.y, m);
    acc.z += __shfl_xor(acc.z, m);
    acc.w += __shfl_xor(acc.w, m);
    ssum += __shfl_xor(ssum, m);
  }
  float4 b4 = *(const float4*)(b0 + (size_t)n * DD + q * 4);
  float inv = (s1 > s0) ? 1.f / ssum : 0.f;
  float4 o;
  o.x = b4.x + acc.x * inv;
  o.y = b4.y + acc.y * inv;
  o.z = b4.z + acc.z * inv;
  o.w = b4.w + acc.w * inv;

  int sl = lane >> 2, c = lane & 3;
  float ox = __shfl(o.x, sl);
  float oy = __shfl(o.y, sl);
  float oz = __shfl(o.z, sl);
  float ow = __shfl(o.w, sl);
  float xv = (c == 0) ? ox : (c == 1) ? oy : (c == 2) ? oz : ow;
  xv = fmaxf(xv, 0.f);  // relu between layers

  const float* wbase = w1 + (size_t)n * DD * DD;
  float4 macc = make_float4(0.f, 0.f, 0.f, 0.f);
#pragma unroll
  for (int ib = 0; ib < 16; ++ib) {
    float4 wv = nt_load4(wbase + (size_t)(ib * 64 + lane) * 4);
    float xi = __shfl(xv, ib * 4 + g);
    macc.x += xi * wv.x;
    macc.y += xi * wv.y;
    macc.z += xi * wv.z;
    macc.w += xi * wv.w;
  }
#pragma unroll
  for (int m = 16; m <= 32; m <<= 1) {
    macc.x += __shfl_xor(macc.x, m);
    macc.y += __shfl_xor(macc.y, m);
    macc.z += __shfl_xor(macc.z, m);
    macc.w += __shfl_xor(macc.w, m);
  }
  if (lane < 16) {
    *(float4*)(h2 + (size_t)n * DD + q * 4) = macc;
    h4v hv = {(_Float16)macc.x, (_Float16)macc.y, (_Float16)macc.z, (_Float16)macc.w};
    *(h4v*)(h2h + (size_t)n * DD + q * 4) = hv;
  }
  const float4* a4 = (const float4*)(a1 + (size_t)n * 2 * DD);
  float4 av1 = a4[q];
  float p2 = macc.x * av1.x + macc.y * av1.y + macc.z * av1.z + macc.w * av1.w;
  if (lane >= 16) p2 = 0.f;
#pragma unroll
  for (int m = 1; m < 64; m <<= 1) p2 += __shfl_xor(p2, m);
  if (lane == 0) s_self2[n] = p2;
}

// ---------------- layer-2 aggregate -> d_out ----------------

__global__ __launch_bounds__(256) void gat_agg(const float* __restrict__ h,
                                               const _Float16* __restrict__ hh,
                                               const float* __restrict__ s_self,
                                               const _Float16* __restrict__ ah,
                                               const int* __restrict__ offs,
                                               const int* __restrict__ src,
                                               const float* __restrict__ bias,
                                               float* __restrict__ out) {
  int widx = threadIdx.x >> 6;
  int lane = threadIdx.x & 63;
  int n = blockIdx.x * 4 + widx;
  int g = lane >> 4;
  int q = lane & 15;

  float4 hn = *(const float4*)(h + (size_t)n * DD + q * 4);

  int s0 = offs[n], s1 = offs[n + 1];
  float4 acc = make_float4(0.f, 0.f, 0.f, 0.f);
  float ssum = 0.f;
  agg_edges(hh, s_self, ah, src, s0, s1, g, q, hn, acc, ssum);
#pragma unroll
  for (int m = 16; m <= 32; m <<= 1) {
    acc.x += __shfl_xor(acc.x, m);
    acc.y += __shfl_xor(acc.y, m);
    acc.z += __shfl_xor(acc.z, m);
    acc.w += __shfl_xor(acc.w, m);
    ssum += __shfl_xor(ssum, m);
  }
  if (lane < 16) {
    float4 b4 = *(const float4*)(bias + (size_t)n * DD + q * 4);
    float inv = (s1 > s0) ? 1.f / ssum : 0.f;
    float4 o;
    o.x = b4.x + acc.x * inv;
    o.y = b4.y + acc.y * inv;
    o.z = b4.z + acc.z * inv;
    o.w = b4.w + acc.w * inv;
    *(float4*)(out + (size_t)n * DD + q * 4) = o;
  }
}

// ---------------- launch ----------------

extern "C" void kernel_launch(void* const* d_in, const int* in_sizes, int n_in,
                              void* d_out, int out_size, void* d_ws, size_t ws_size,
                              hipStream_t stream) {
  const float* x = (const float*)d_in[0];
  const int* edge = (const int*)d_in[1];
  const float* w0 = (const float*)d_in[2];
  const float* a0 = (const float*)d_in[3];
  const float* b0 = (const float*)d_in[4];
  const float* w1 = (const float*)d_in[5];
  const float* a1 = (const float*)d_in[6];
  const float* b1 = (const float*)d_in[7];
  float* out = (float*)d_out;

  const int* row = edge;       // edge_index[0]
  const int* col = edge + EE;  // edge_index[1]

  char* p = (char*)d_ws;
  float* h1 = (float*)p;        p += (size_t)NN * DD * 4;
  float* h2 = (float*)p;        p += (size_t)NN * DD * 4;
  _Float16* h1h = (_Float16*)p; p += (size_t)NN * DD * 2;
  _Float16* h2h = (_Float16*)p; p += (size_t)NN * DD * 2;
  _Float16* a0h = (_Float16*)p; p += (size_t)NN * DD * 2;
  _Float16* a1h = (_Float16*)p; p += (size_t)NN * DD * 2;
  float* s_self1 = (float*)p;   p += (size_t)NN * 4;
  float* s_self2 = (float*)p;   p += (size_t)NN * 4;
  int* deg = (int*)p;           p += (size_t)NN * 4;
  int* offs = (int*)p;          p += (size_t)(NN + 1) * 4;
  int* cursor = (int*)p;        p += (size_t)NN * 4;
  int* src = (int*)p;           p += (size_t)EE * 4;

  hipMemsetAsync(deg, 0, (size_t)NN * 4, stream);

  // CSR build + fp16 conversions co-scheduled with layer-1 matvec
  k1_count_h<<<CNT_BLK + K1_HBLK + CVT_BLK, 256, 0, stream>>>(col, deg, x, w0, a0, a1,
                                                              h1, h1h, s_self1, a0h, a1h);
  k2_scan_h<<<1 + K2_HBLK, 1024, 0, stream>>>(deg, offs, cursor, x, w0, a0, h1, h1h, s_self1);
  k3_scatter_h<<<CNT_BLK + K3_HBLK, 256, 0, stream>>>(row, col, cursor, src, x, w0, a0,
                                                      h1, h1h, s_self1);

  // layer-1 aggregate (fp16 gathers) fused with layer-2 matvec
  fused_agg_h<<<NN / 4, 256, 0, stream>>>(h1, h1h, s_self1, a0h, offs, src, b0,
                                          w1, a1, h2, h2h, s_self2);
  // layer-2 aggregate (fp16 gathers) -> out
  gat_agg<<<NN / 4, 256, 0, stream>>>(h2, h2h, s_self2, a1h, offs, src, b1, out);
}